// Round 1
// baseline (208.293 us; speedup 1.0000x reference)
//
#include <hip/hip_runtime.h>

// BDToGEConverter: out[b,s,p,d] = sum_k W[p,d,k] * x[b,s,k], W fixed & sparse.
// Per row (1280 outputs) only 84 nonzero:
//   p=0: d0 = sum k*x[64+k],  d1 = sum k*x[96+k]      (k=0..15)
//   p=1: d0 = sum k*x[80+k],  d1 = sum k*x[112+k]
//   all p, d=25..34: {x16,x17,x10,x11,x12,x13,x14,x15,x18,x19}
// One wave per row: coalesced loads of just the needed lines, shfl-xor
// butterfly for the 4 dots, shfl broadcasts for the taps, 5 coalesced
// float4 stores per lane (1 KB/wave/store, full-line, no RMW).
//
// R1 fix: in_sizes[0] is (evidence says) BYTES, so in_sizes[0]/512 = 131072
// = 4x the logical row count -> previous version wrote 671 MB (matching the
// 655360 KB poison fill and the ~103 us kernel time) instead of 167.8 MB.
// The problem shape is fixed (B=8, S=4096 -> 32768 rows); clamp to it.
// Correct under either units convention.
// Roofline: 167.8 MB writes + ~12.6 MB reads ~= 29 us @ 6.3 TB/s.

#define BD_DIM 512
#define ROW_F4 320            // 8*160 floats / 4
#define N_ROWS_LOGICAL 32768  // B*S = 8*4096, fixed by the problem spec

__global__ __launch_bounds__(256) void bd2ge_kernel(
    const float* __restrict__ x, float* __restrict__ out, int n_rows)
{
    const int wave = threadIdx.x >> 6;
    const int lane = threadIdx.x & 63;
    const int row  = blockIdx.x * 4 + wave;
    if (row >= n_rows) return;

    const float* __restrict__ xr = x + (size_t)row * BD_DIM;

    // Opcode taps live in x[10..19] (cache line 0 of the row). Guard the load
    // to lanes <20 so line 1 (x[32..63], unused) is never fetched.
    float xa = 0.f;
    if (lane < 20) xa = xr[lane];
    // Nibble blocks x[64..127] (lines 2,3) — fully used.
    const float xb = xr[64 + lane];

    // Dots: t = (lane&15)*xb, butterfly-sum within each 16-lane group.
    float t = (float)(lane & 15) * xb;
    t += __shfl_xor(t, 1);
    t += __shfl_xor(t, 2);
    t += __shfl_xor(t, 4);
    t += __shfl_xor(t, 8);
    const float dA0 = __shfl(t, 0);   // ALU_LO      -> p=0, d=0
    const float dA1 = __shfl(t, 16);  // ALU_HI      -> p=1, d=0
    const float dB0 = __shfl(t, 32);  // AX_CARRY_LO -> p=0, d=1
    const float dB1 = __shfl(t, 48);  // AX_CARRY_HI -> p=1, d=1

    // Opcode taps broadcast (d = OP_START + ge_op).
    const float o25 = __shfl(xa, 16);
    const float o26 = __shfl(xa, 17);
    const float o27 = __shfl(xa, 10);
    const float o28 = __shfl(xa, 11);
    const float o29 = __shfl(xa, 12);
    const float o30 = __shfl(xa, 13);
    const float o31 = __shfl(xa, 14);
    const float o32 = __shfl(xa, 15);
    const float o33 = __shfl(xa, 18);
    const float o34 = __shfl(xa, 19);

    float4* __restrict__ orow = (float4*)(out + (size_t)row * (ROW_F4 * 4));

    #pragma unroll
    for (int j = 0; j < 5; ++j) {
        const int f = lane + j * 64;       // float4 index in [0,320)
        const int p = f / 40;              // position (40 float4 per p)
        const int q = f - p * 40;          // d = 4q..4q+3
        float4 v;
        v.x = (q == 0) ? (p == 0 ? dA0 : (p == 1 ? dA1 : 0.f))
                       : (q == 7 ? o28 : (q == 8 ? o32 : 0.f));
        v.y = (q == 0) ? (p == 0 ? dB0 : (p == 1 ? dB1 : 0.f))
                       : (q == 6 ? o25 : (q == 7 ? o29 : (q == 8 ? o33 : 0.f)));
        v.z = (q == 6) ? o26 : (q == 7 ? o30 : (q == 8 ? o34 : 0.f));
        v.w = (q == 6) ? o27 : (q == 7 ? o31 : 0.f);
        orow[f] = v;
    }
}

extern "C" void kernel_launch(void* const* d_in, const int* in_sizes, int n_in,
                              void* d_out, int out_size, void* d_ws, size_t ws_size,
                              hipStream_t stream)
{
    const float* x = (const float*)d_in[0];     // [B,S,512] fp32
    // d_in[1] = W_proj: fixed sparse tensor, fully hardcoded above — never read.
    float* out = (float*)d_out;                 // [B,S,8,160] fp32

    // in_sizes[0]/BD_DIM is 32768 if in_sizes is element-count, 131072 if it
    // is bytes. The logical row count is fixed at 32768; taking the min is
    // correct either way and avoids writing the 4x guard/poison region.
    int n_rows = in_sizes[0] / BD_DIM;
    if (n_rows > N_ROWS_LOGICAL) n_rows = N_ROWS_LOGICAL;

    const int blocks = (n_rows + 3) / 4;        // 4 rows (waves) per 256-thread block
    bd2ge_kernel<<<blocks, 256, 0, stream>>>(x, out, n_rows);
}

// Round 3
// 207.809 us; speedup vs baseline: 1.0023x; 1.0023x over previous
//
#include <hip/hip_runtime.h>

// BDToGEConverter: out[b,s,p,d] = sum_k W[p,d,k] * x[b,s,k], W fixed & sparse.
// Per row (1280 outputs) only 84 nonzero:
//   p=0: d0 = sum k*x[64+k],  d1 = sum k*x[96+k]      (k=0..15)
//   p=1: d0 = sum k*x[80+k],  d1 = sum k*x[112+k]
//   all p, d=25..34: {x16,x17,x10,x11,x12,x13,x14,x15,x18,x19}
// One wave per row: coalesced loads of just the needed lines, shfl-xor
// butterfly for the 4 dots, shfl broadcasts for the taps, 5 coalesced
// 16B stores per lane (1 KB/wave/store, full-line, no RMW).
//
// R1 established: in_sizes[0] is ELEMENT count (clamp was a no-op; dur
// unchanged at 208.3). Kernel has always written the logical 167.8 MB.
// R2 failed to compile: __builtin_nontemporal_store rejects HIP_vector_type
// float4. R3: same probe via clang native ext_vector_type(4).
// If the kernel is secretly ~100 us due to L2 write-allocate on the
// 167.8 MB stream, nt stores recover it; if dur_us is unchanged, the kernel
// is at its ~28 us write roofline and the 208 us floor is harness-owned
// (poison fill ~105 us + restore dispatches), i.e. ROOFLINE.
// Roofline: 167.8 MB writes + ~12.6 MB reads ~= 29 us @ 6.3 TB/s.

#define BD_DIM 512
#define ROW_F4 320            // 8*160 floats / 4
#define N_ROWS_LOGICAL 32768  // B*S = 8*4096, fixed by the problem spec

typedef float vfloat4 __attribute__((ext_vector_type(4)));  // native vector: nt-store legal

__global__ __launch_bounds__(256) void bd2ge_kernel(
    const float* __restrict__ x, float* __restrict__ out, int n_rows)
{
    const int wave = threadIdx.x >> 6;
    const int lane = threadIdx.x & 63;
    const int row  = blockIdx.x * 4 + wave;
    if (row >= n_rows) return;

    const float* __restrict__ xr = x + (size_t)row * BD_DIM;

    // Opcode taps live in x[10..19] (cache line 0 of the row). Guard the load
    // to lanes <20 so line 1 (x[32..63], unused) is never fetched.
    float xa = 0.f;
    if (lane < 20) xa = xr[lane];
    // Nibble blocks x[64..127] (lines 2,3) — fully used.
    const float xb = xr[64 + lane];

    // Dots: t = (lane&15)*xb, butterfly-sum within each 16-lane group.
    float t = (float)(lane & 15) * xb;
    t += __shfl_xor(t, 1);
    t += __shfl_xor(t, 2);
    t += __shfl_xor(t, 4);
    t += __shfl_xor(t, 8);
    const float dA0 = __shfl(t, 0);   // ALU_LO      -> p=0, d=0
    const float dA1 = __shfl(t, 16);  // ALU_HI      -> p=1, d=0
    const float dB0 = __shfl(t, 32);  // AX_CARRY_LO -> p=0, d=1
    const float dB1 = __shfl(t, 48);  // AX_CARRY_HI -> p=1, d=1

    // Opcode taps broadcast (d = OP_START + ge_op).
    const float o25 = __shfl(xa, 16);
    const float o26 = __shfl(xa, 17);
    const float o27 = __shfl(xa, 10);
    const float o28 = __shfl(xa, 11);
    const float o29 = __shfl(xa, 12);
    const float o30 = __shfl(xa, 13);
    const float o31 = __shfl(xa, 14);
    const float o32 = __shfl(xa, 15);
    const float o33 = __shfl(xa, 18);
    const float o34 = __shfl(xa, 19);

    vfloat4* __restrict__ orow = (vfloat4*)(out + (size_t)row * (ROW_F4 * 4));

    #pragma unroll
    for (int j = 0; j < 5; ++j) {
        const int f = lane + j * 64;       // float4 index in [0,320)
        const int p = f / 40;              // position (40 float4 per p)
        const int q = f - p * 40;          // d = 4q..4q+3
        vfloat4 v;
        v.x = (q == 0) ? (p == 0 ? dA0 : (p == 1 ? dA1 : 0.f))
                       : (q == 7 ? o28 : (q == 8 ? o32 : 0.f));
        v.y = (q == 0) ? (p == 0 ? dB0 : (p == 1 ? dB1 : 0.f))
                       : (q == 6 ? o25 : (q == 7 ? o29 : (q == 8 ? o33 : 0.f)));
        v.z = (q == 6) ? o26 : (q == 7 ? o30 : (q == 8 ? o34 : 0.f));
        v.w = (q == 6) ? o27 : (q == 7 ? o31 : 0.f);
        // Write-once stream, never re-read by this kernel: bypass L2
        // write-allocate with nontemporal hint (sets nt on the dwordx4 store).
        __builtin_nontemporal_store(v, &orow[f]);
    }
}

extern "C" void kernel_launch(void* const* d_in, const int* in_sizes, int n_in,
                              void* d_out, int out_size, void* d_ws, size_t ws_size,
                              hipStream_t stream)
{
    const float* x = (const float*)d_in[0];     // [B,S,512] fp32
    // d_in[1] = W_proj: fixed sparse tensor, fully hardcoded above — never read.
    float* out = (float*)d_out;                 // [B,S,8,160] fp32

    // in_sizes[0] is an element count (established R1: clamp was a no-op);
    // keep the clamp anyway — correct under either convention.
    int n_rows = in_sizes[0] / BD_DIM;
    if (n_rows > N_ROWS_LOGICAL) n_rows = N_ROWS_LOGICAL;

    const int blocks = (n_rows + 3) / 4;        // 4 rows (waves) per 256-thread block
    bd2ge_kernel<<<blocks, 256, 0, stream>>>(x, out, n_rows);
}